// Round 4
// baseline (131.765 us; speedup 1.0000x reference)
//
#include <hip/hip_runtime.h>
#include <math.h>

#define NFFT   1024
#define FREQ   513
#define FRAMES 256
#define SIGLEN 66560          // 256*256 + 1024
#define NB     4
#define BFT    (NB * FREQ * FRAMES)   // 525312

// ---------------------------------------------------------------------------
// perm = argsort(theta) DESCENDING, stable (O(F^2) rank). Needs 2052 B of ws.
// ---------------------------------------------------------------------------
__global__ __launch_bounds__(256)
void dstft_perm(const float* __restrict__ raw_win, int* __restrict__ perm)
{
    __shared__ float th[FREQ];
    const int tid = threadIdx.x;
    for (int i = tid; i < FREQ; i += 256)
        th[i] = 10.0f + 1014.0f / (1.0f + expf(-raw_win[i]));
    __syncthreads();
    for (int i = tid; i < FREQ; i += 256) {
        const float ti = th[i];
        int r = 0;
        for (int j = 0; j < FREQ; ++j) {
            const float tj = th[j];
            r += (tj > ti) || (tj == ti && j < i);   // descending, stable
        }
        perm[r] = i;
    }
}

__device__ __forceinline__ float sigmoid_f32(float v)
{
    if (v >= 0.0f) {
        return 1.0f / (1.0f + expf(-v));
    } else {
        const float e = expf(v);
        return e / (1.0f + e);
    }
}

// ---------------------------------------------------------------------------
// One 64-lane wave per (t, chunk of 64 sorted f's). Lanes share t -> x loads
// are same-address broadcasts. Window via v_cos (revolutions, |arg|<=0.5).
// DFT phasor: init+step via libm double sincos; rotation recurrence inside.
// STFT_MODE: 1 = real-part-only at out[BFT+idx]; 2 = interleaved (re,im).
// ---------------------------------------------------------------------------
__global__ __launch_bounds__(64)
void dstft_main(const float* __restrict__ x,
                const float* __restrict__ raw_win,
                const float* __restrict__ raw_hop,
                const int* __restrict__ perm,      // may be null (unsorted)
                float* __restrict__ out, int out_size, int stft_mode)
{
    const int t    = blockIdx.y;
    const int lane = threadIdx.x;
    const int spos = blockIdx.x * 64 + lane;
    const bool active = (spos < FREQ);

    int f = 0;
    if (active) {
        f = perm ? perm[spos] : spos;
        f = (f < 0) ? 0 : ((f > FREQ - 1) ? (FREQ - 1) : f);  // fault-proof
    }
    const float theta = active
        ? (10.0f + sigmoid_f32(raw_win[f]) * 1014.0f)
        : 10.0f;

    float tmax = theta;
#pragma unroll
    for (int s = 32; s; s >>= 1) tmax = fmaxf(tmax, __shfl_xor(tmax, s, 64));

    // pos/floor: f32-canonical replication of the reference
    const float hop = 1.0f + sigmoid_f32(raw_hop[0]) * 255.0f;
    float pos = (float)t * hop;
    pos = fminf(fmaxf(pos, 0.0f), 65536.0f);     // clip(pos, 0, L-N_FFT)
    const float fl   = floorf(pos);
    const int   base = (int)fl;
    const float frac = pos - fl;
    const float c    = 511.5f + frac;            // (N-1)/2 + frac

    int lo = (int)floorf(c - 0.5f * tmax);
    int hi = (int)ceilf (c + 0.5f * tmax);
    lo = lo > 0 ? lo : 0;
    hi = hi < (NFFT - 1) ? hi : (NFFT - 1);
    int cnt = hi - lo + 1;
    cnt = cnt < 0 ? 0 : (cnt > NFFT ? NFFT : cnt);

    const float invth = 1.0f / theta;
    float r = ((float)lo - c) * invth;           // window arg, revolutions

    // DFT phasor init & step (radians, double, exact)
    const double TWO_PI_OVER_N = 6.283185307179586476925286766559 / 1024.0;
    double sd_d, cd_d, sa_d, ca_d;
    sincos((double)f * TWO_PI_OVER_N, &sd_d, &cd_d);
    const int m0 = (f * lo) & (NFFT - 1);
    sincos((double)m0 * TWO_PI_OVER_N, &sa_d, &ca_d);
    const float cd = (float)cd_d, sd = (float)sd_d;
    float ca = (float)ca_d, sa = (float)sa_d;

    const float* xp0 = x + base + lo;
    const float* xp1 = xp0 + SIGLEN;
    const float* xp2 = xp1 + SIGLEN;
    const float* xp3 = xp2 + SIGLEN;

    float re0 = 0.f, re1 = 0.f, re2 = 0.f, re3 = 0.f;
    float sm0 = 0.f, sm1 = 0.f, sm2 = 0.f, sm3 = 0.f;

#pragma unroll 4
    for (int i = 0; i < cnt; ++i) {
        const float cw = __builtin_amdgcn_cosf(r);        // cos(2*pi*r)
        const float w  = (fabsf(r) <= 0.5f) ? fmaf(0.5f, cw, 0.5f) : 0.0f;
        const float wc  = w * ca;
        const float wsn = w * sa;
        const float v0 = xp0[i];
        const float v1 = xp1[i];
        const float v2 = xp2[i];
        const float v3 = xp3[i];
        re0 = fmaf(v0, wc, re0);  sm0 = fmaf(v0, wsn, sm0);
        re1 = fmaf(v1, wc, re1);  sm1 = fmaf(v1, wsn, sm1);
        re2 = fmaf(v2, wc, re2);  sm2 = fmaf(v2, wsn, sm2);
        re3 = fmaf(v3, wc, re3);  sm3 = fmaf(v3, wsn, sm3);
        const float nca = fmaf(ca, cd, -(sa * sd));
        const float nsa = fmaf(sa, cd,   ca * sd);
        ca = nca; sa = nsa;
        r += invth;
    }

    if (active) {
        const float res[4] = { re0, re1, re2, re3 };
        const float sms[4] = { sm0, sm1, sm2, sm3 };
        const int ftBase = f * FRAMES + t;
#pragma unroll
        for (int b = 0; b < NB; ++b) {
            const int   idx = b * (FREQ * FRAMES) + ftBase;
            const float re  = res[b];
            const float im  = -sms[b];
            if (idx < out_size)
                out[idx] = sqrtf(fmaf(re, re, im * im)) + 1e-12f;   // spec
            if (stft_mode == 2) {
                // complex as interleaved (re,im) float pairs
                if (BFT + 2 * idx + 1 < out_size) {
                    out[BFT + 2 * idx]     = re;
                    out[BFT + 2 * idx + 1] = im;
                }
            } else {
                // complex materialized as float32 real part only
                if (BFT + idx < out_size)
                    out[BFT + idx] = re;
            }
        }
    }
}

// ---------------------------------------------------------------------------
extern "C" void kernel_launch(void* const* d_in, const int* in_sizes, int n_in,
                              void* d_out, int out_size, void* d_ws, size_t ws_size,
                              hipStream_t stream)
{
    const float* x       = (const float*)d_in[0];
    const float* raw_win = (const float*)d_in[1];
    const float* raw_hop = (const float*)d_in[2];
    float* out = (float*)d_out;

    int* perm = nullptr;
    if (d_ws != nullptr && ws_size >= 4096) {
        perm = (int*)d_ws;
        dstft_perm<<<1, 256, 0, stream>>>(raw_win, perm);
    }
    // out_size >= 3*BFT -> room for interleaved complex pairs; otherwise the
    // harness materialized the complex output as real-part-only f32.
    const int stft_mode = (out_size >= 3 * BFT) ? 2 : 1;
    dstft_main<<<dim3(9, FRAMES), 64, 0, stream>>>(x, raw_win, raw_hop,
                                                   perm, out, out_size,
                                                   stft_mode);
}

// Round 5
// 88.131 us; speedup vs baseline: 1.4951x; 1.4951x over previous
//
#include <hip/hip_runtime.h>
#include <math.h>

#define NFFT   1024
#define FREQ   513
#define FRAMES 256
#define SIGLEN 66560          // 256*256 + 1024
#define NB     4
#define BFT    (NB * FREQ * FRAMES)   // 525312
#define NWAVE  4               // waves per block (n-loop split factor)

// ---------------------------------------------------------------------------
// perm = argsort(theta) DESCENDING, stable (O(F^2) rank). Needs 2052 B of ws.
// ---------------------------------------------------------------------------
__global__ __launch_bounds__(512)
void dstft_perm(const float* __restrict__ raw_win, int* __restrict__ perm)
{
    __shared__ float th[FREQ];
    const int tid = threadIdx.x;
    for (int i = tid; i < FREQ; i += 512)
        th[i] = 10.0f + 1014.0f / (1.0f + expf(-raw_win[i]));
    __syncthreads();
    for (int i = tid; i < FREQ; i += 512) {
        const float ti = th[i];
        int r = 0;
        for (int j = 0; j < FREQ; ++j) {
            const float tj = th[j];
            r += (tj > ti) || (tj == ti && j < i);   // descending, stable
        }
        perm[r] = i;
    }
}

__device__ __forceinline__ float sigmoid_f32(float v)
{
    if (v >= 0.0f) {
        return 1.0f / (1.0f + expf(-v));
    } else {
        const float e = expf(v);
        return e / (1.0f + e);
    }
}

// ---------------------------------------------------------------------------
// Block = 256 threads = 4 waves, all serving the same (t, 64-f chunk).
// Wave q takes the q-th quarter of the window support [lo,hi]; each segment
// gets an exact phasor init (libm double sincos), rotation recurrence inside.
// Partials combined through LDS; wave 0 writes outputs.
// ---------------------------------------------------------------------------
__global__ __launch_bounds__(64 * NWAVE)
void dstft_main(const float* __restrict__ x,
                const float* __restrict__ raw_win,
                const float* __restrict__ raw_hop,
                const int* __restrict__ perm,      // may be null (unsorted)
                float* __restrict__ out, int out_size, int stft_mode)
{
    const int t    = blockIdx.y;
    const int tid  = threadIdx.x;
    const int lane = tid & 63;
    const int q    = tid >> 6;               // wave id = n-segment id
    const int spos = blockIdx.x * 64 + lane;
    const bool active = (spos < FREQ);

    int f = 0;
    if (active) {
        f = perm ? perm[spos] : spos;
        f = (f < 0) ? 0 : ((f > FREQ - 1) ? (FREQ - 1) : f);  // fault-proof
    }
    const float theta = active
        ? (10.0f + sigmoid_f32(raw_win[f]) * 1014.0f)
        : 10.0f;

    // wave-wide max theta (same lanes->same f in every wave -> same result)
    float tmax = theta;
#pragma unroll
    for (int s = 32; s; s >>= 1) tmax = fmaxf(tmax, __shfl_xor(tmax, s, 64));

    // pos/floor: f32-canonical replication of the reference
    const float hop = 1.0f + sigmoid_f32(raw_hop[0]) * 255.0f;
    float pos = (float)t * hop;
    pos = fminf(fmaxf(pos, 0.0f), 65536.0f);     // clip(pos, 0, L-N_FFT)
    const float fl   = floorf(pos);
    const int   base = (int)fl;
    const float frac = pos - fl;
    const float c    = 511.5f + frac;            // (N-1)/2 + frac

    int lo = (int)floorf(c - 0.5f * tmax);
    int hi = (int)ceilf (c + 0.5f * tmax);
    lo = lo > 0 ? lo : 0;
    hi = hi < (NFFT - 1) ? hi : (NFFT - 1);
    int cnt = hi - lo + 1;
    cnt = cnt < 0 ? 0 : (cnt > NFFT ? NFFT : cnt);

    // this wave's n-segment [s0, s0+segcnt)
    const int s0     = lo + (cnt * q) / NWAVE;
    const int s1     = lo + (cnt * (q + 1)) / NWAVE;
    const int segcnt = s1 - s0;

    const float invth = 1.0f / theta;
    float r = ((float)s0 - c) * invth;           // window arg, revolutions

    // phasor init at n = s0 and per-sample step (radians, double, exact)
    const double TWO_PI_OVER_N = 6.283185307179586476925286766559 / 1024.0;
    double sd_d, cd_d, sa_d, ca_d;
    sincos((double)f * TWO_PI_OVER_N, &sd_d, &cd_d);
    const int m0 = (f * s0) & (NFFT - 1);
    sincos((double)m0 * TWO_PI_OVER_N, &sa_d, &ca_d);
    const float cd = (float)cd_d, sd = (float)sd_d;
    float ca = (float)ca_d, sa = (float)sa_d;

    const float* xp0 = x + base + s0;
    const float* xp1 = xp0 + SIGLEN;
    const float* xp2 = xp1 + SIGLEN;
    const float* xp3 = xp2 + SIGLEN;

    float re0 = 0.f, re1 = 0.f, re2 = 0.f, re3 = 0.f;
    float sm0 = 0.f, sm1 = 0.f, sm2 = 0.f, sm3 = 0.f;

#pragma unroll 4
    for (int i = 0; i < segcnt; ++i) {
        const float cw = __builtin_amdgcn_cosf(r);        // cos(2*pi*r)
        const float w  = (fabsf(r) <= 0.5f) ? fmaf(0.5f, cw, 0.5f) : 0.0f;
        const float wc  = w * ca;
        const float wsn = w * sa;
        const float v0 = xp0[i];
        const float v1 = xp1[i];
        const float v2 = xp2[i];
        const float v3 = xp3[i];
        re0 = fmaf(v0, wc, re0);  sm0 = fmaf(v0, wsn, sm0);
        re1 = fmaf(v1, wc, re1);  sm1 = fmaf(v1, wsn, sm1);
        re2 = fmaf(v2, wc, re2);  sm2 = fmaf(v2, wsn, sm2);
        re3 = fmaf(v3, wc, re3);  sm3 = fmaf(v3, wsn, sm3);
        const float nca = fmaf(ca, cd, -(sa * sd));
        const float nsa = fmaf(sa, cd,   ca * sd);
        ca = nca; sa = nsa;
        r += invth;
    }

    // ---- cross-wave combine via LDS (pad 9 to dodge bank conflicts) ----
    __shared__ float part[NWAVE][64][9];
    part[q][lane][0] = re0;  part[q][lane][1] = re1;
    part[q][lane][2] = re2;  part[q][lane][3] = re3;
    part[q][lane][4] = sm0;  part[q][lane][5] = sm1;
    part[q][lane][6] = sm2;  part[q][lane][7] = sm3;
    __syncthreads();

    if (tid < 64 && active) {                 // wave 0: lane==tid, f valid
        float res[NB], sms[NB];
#pragma unroll
        for (int b = 0; b < NB; ++b) {
            res[b] = part[0][tid][b]     + part[1][tid][b]
                   + part[2][tid][b]     + part[3][tid][b];
            sms[b] = part[0][tid][4 + b] + part[1][tid][4 + b]
                   + part[2][tid][4 + b] + part[3][tid][4 + b];
        }
        const int ftBase = f * FRAMES + t;
#pragma unroll
        for (int b = 0; b < NB; ++b) {
            const int   idx = b * (FREQ * FRAMES) + ftBase;
            const float re  = res[b];
            const float im  = -sms[b];
            if (idx < out_size)
                out[idx] = sqrtf(fmaf(re, re, im * im)) + 1e-12f;   // spec
            if (stft_mode == 2) {
                if (BFT + 2 * idx + 1 < out_size) {
                    out[BFT + 2 * idx]     = re;
                    out[BFT + 2 * idx + 1] = im;
                }
            } else {
                if (BFT + idx < out_size)
                    out[BFT + idx] = re;      // complex stored as f32 real
            }
        }
    }
}

// ---------------------------------------------------------------------------
extern "C" void kernel_launch(void* const* d_in, const int* in_sizes, int n_in,
                              void* d_out, int out_size, void* d_ws, size_t ws_size,
                              hipStream_t stream)
{
    const float* x       = (const float*)d_in[0];
    const float* raw_win = (const float*)d_in[1];
    const float* raw_hop = (const float*)d_in[2];
    float* out = (float*)d_out;

    int* perm = nullptr;
    if (d_ws != nullptr && ws_size >= 4096) {
        perm = (int*)d_ws;
        dstft_perm<<<1, 512, 0, stream>>>(raw_win, perm);
    }
    const int stft_mode = (out_size >= 3 * BFT) ? 2 : 1;
    dstft_main<<<dim3(9, FRAMES), 64 * NWAVE, 0, stream>>>(
        x, raw_win, raw_hop, perm, out, out_size, stft_mode);
}

// Round 6
// 87.118 us; speedup vs baseline: 1.5125x; 1.0116x over previous
//
#include <hip/hip_runtime.h>
#include <math.h>

#define NFFT   1024
#define FREQ   513
#define FRAMES 256
#define SIGLEN 66560          // 256*256 + 1024
#define NB     4
#define BFT    (NB * FREQ * FRAMES)   // 525312
#define NWAVE  8               // waves per block (n-loop split factor)

// ---------------------------------------------------------------------------
// perm = argsort(theta) DESCENDING, stable (O(F^2) rank). Needs 2052 B of ws.
// ---------------------------------------------------------------------------
__global__ __launch_bounds__(512)
void dstft_perm(const float* __restrict__ raw_win, int* __restrict__ perm)
{
    __shared__ float th[FREQ];
    const int tid = threadIdx.x;
    for (int i = tid; i < FREQ; i += 512)
        th[i] = 10.0f + 1014.0f / (1.0f + expf(-raw_win[i]));
    __syncthreads();
    for (int i = tid; i < FREQ; i += 512) {
        const float ti = th[i];
        int r = 0;
        for (int j = 0; j < FREQ; ++j) {
            const float tj = th[j];
            r += (tj > ti) || (tj == ti && j < i);   // descending, stable
        }
        perm[r] = i;
    }
}

__device__ __forceinline__ float sigmoid_f32(float v)
{
    if (v >= 0.0f) {
        return 1.0f / (1.0f + expf(-v));
    } else {
        const float e = expf(v);
        return e / (1.0f + e);
    }
}

__device__ __forceinline__ float rfl_f32(float v)
{
    return __int_as_float(__builtin_amdgcn_readfirstlane(__float_as_int(v)));
}

// ---------------------------------------------------------------------------
// Block = 8 waves, all serving the same (t, 64-f chunk). Wave q takes the
// q-th eighth of the window support [lo,hi]. All loop bounds / addresses are
// forced wave-uniform (readfirstlane) -> scalar loads, scalar loop control.
// Phasor init & step: exact integer range reduction + hw v_cos/v_sin
// (revolutions). Partials combined via LDS; wave 0 writes outputs.
// ---------------------------------------------------------------------------
__global__ __launch_bounds__(64 * NWAVE)
void dstft_main(const float* __restrict__ x,
                const float* __restrict__ raw_win,
                const float* __restrict__ raw_hop,
                const int* __restrict__ perm,      // may be null (unsorted)
                float* __restrict__ out, int out_size, int stft_mode)
{
    const int t    = blockIdx.y;
    const int tid  = threadIdx.x;
    const int lane = tid & 63;
    const int q    = tid >> 6;               // wave id = n-segment id
    const int spos = blockIdx.x * 64 + lane;
    const bool active = (spos < FREQ);

    int f = 0;
    if (active) {
        f = perm ? perm[spos] : spos;
        f = (f < 0) ? 0 : ((f > FREQ - 1) ? (FREQ - 1) : f);  // fault-proof
    }
    const float theta = active
        ? (10.0f + sigmoid_f32(raw_win[f]) * 1014.0f)
        : 10.0f;

    // wave-wide max theta -> force into SGPR (uniformity for the compiler)
    float tmaxv = theta;
#pragma unroll
    for (int s = 32; s; s >>= 1) tmaxv = fmaxf(tmaxv, __shfl_xor(tmaxv, s, 64));
    const float tmax = rfl_f32(tmaxv);

    // pos/floor: f32-canonical replication of the reference (all uniform)
    const float hop = 1.0f + sigmoid_f32(raw_hop[0]) * 255.0f;
    float pos = (float)t * hop;
    pos = fminf(fmaxf(pos, 0.0f), 65536.0f);     // clip(pos, 0, L-N_FFT)
    const float fl = floorf(pos);
    const int   base = __builtin_amdgcn_readfirstlane((int)fl);
    const float c    = rfl_f32(511.5f + (pos - fl));   // (N-1)/2 + frac

    int lo = (int)floorf(c - 0.5f * tmax);
    int hi = (int)ceilf (c + 0.5f * tmax);
    lo = lo > 0 ? lo : 0;
    hi = hi < (NFFT - 1) ? hi : (NFFT - 1);
    int cnt = hi - lo + 1;
    cnt = cnt < 0 ? 0 : (cnt > NFFT ? NFFT : cnt);
    lo  = __builtin_amdgcn_readfirstlane(lo);
    cnt = __builtin_amdgcn_readfirstlane(cnt);

    // this wave's n-segment [s0, s1)  (scalar)
    const int s0     = lo + (cnt * q) / NWAVE;
    const int s1     = lo + (cnt * (q + 1)) / NWAVE;
    const int segcnt = s1 - s0;

    const float invth = 1.0f / theta;
    float r = ((float)s0 - c) * invth;           // window arg, revolutions

    // phasor init at n=s0 and step, via exact int reduction + hw trig (rev)
    const float sdr = (float)f * (1.0f / 1024.0f);         // f<=512 -> <=0.5
    const float cd  = __builtin_amdgcn_cosf(sdr);
    const float sd  = __builtin_amdgcn_sinf(sdr);
    int m0 = (f * s0) & (NFFT - 1);
    m0 = (m0 >= 512) ? (m0 - 1024) : m0;                   // [-512, 511]
    const float p0 = (float)m0 * (1.0f / 1024.0f);         // [-0.5, 0.5)
    float ca = __builtin_amdgcn_cosf(p0);
    float sa = __builtin_amdgcn_sinf(p0);

    const float* __restrict__ xb = x + (base + s0);        // uniform base

    float re0 = 0.f, re1 = 0.f, re2 = 0.f, re3 = 0.f;
    float sm0 = 0.f, sm1 = 0.f, sm2 = 0.f, sm3 = 0.f;

#pragma unroll 4
    for (int i = 0; i < segcnt; ++i) {
        const float cw = __builtin_amdgcn_cosf(r);        // cos(2*pi*r)
        const float w  = (fabsf(r) <= 0.5f) ? fmaf(0.5f, cw, 0.5f) : 0.0f;
        const float wc  = w * ca;
        const float wsn = w * sa;
        const float v0 = xb[i];
        const float v1 = xb[i + SIGLEN];
        const float v2 = xb[i + 2 * SIGLEN];
        const float v3 = xb[i + 3 * SIGLEN];
        re0 = fmaf(v0, wc, re0);  sm0 = fmaf(v0, wsn, sm0);
        re1 = fmaf(v1, wc, re1);  sm1 = fmaf(v1, wsn, sm1);
        re2 = fmaf(v2, wc, re2);  sm2 = fmaf(v2, wsn, sm2);
        re3 = fmaf(v3, wc, re3);  sm3 = fmaf(v3, wsn, sm3);
        const float nca = fmaf(ca, cd, -(sa * sd));
        const float nsa = fmaf(sa, cd,   ca * sd);
        ca = nca; sa = nsa;
        r += invth;
    }

    // ---- cross-wave combine via LDS (stride 9 dwords -> 2-way = free) ----
    __shared__ float part[NWAVE][64][9];
    part[q][lane][0] = re0;  part[q][lane][1] = re1;
    part[q][lane][2] = re2;  part[q][lane][3] = re3;
    part[q][lane][4] = sm0;  part[q][lane][5] = sm1;
    part[q][lane][6] = sm2;  part[q][lane][7] = sm3;
    __syncthreads();

    if (tid < 64 && active) {                 // wave 0: lane==tid, f valid
        float res[NB] = {0.f, 0.f, 0.f, 0.f};
        float sms[NB] = {0.f, 0.f, 0.f, 0.f};
#pragma unroll
        for (int p = 0; p < NWAVE; ++p) {
#pragma unroll
            for (int b = 0; b < NB; ++b) {
                res[b] += part[p][tid][b];
                sms[b] += part[p][tid][4 + b];
            }
        }
        const int ftBase = f * FRAMES + t;
#pragma unroll
        for (int b = 0; b < NB; ++b) {
            const int   idx = b * (FREQ * FRAMES) + ftBase;
            const float re  = res[b];
            const float im  = -sms[b];
            if (idx < out_size)
                out[idx] = sqrtf(fmaf(re, re, im * im)) + 1e-12f;   // spec
            if (stft_mode == 2) {
                if (BFT + 2 * idx + 1 < out_size) {
                    out[BFT + 2 * idx]     = re;
                    out[BFT + 2 * idx + 1] = im;
                }
            } else {
                if (BFT + idx < out_size)
                    out[BFT + idx] = re;      // complex stored as f32 real
            }
        }
    }
}

// ---------------------------------------------------------------------------
extern "C" void kernel_launch(void* const* d_in, const int* in_sizes, int n_in,
                              void* d_out, int out_size, void* d_ws, size_t ws_size,
                              hipStream_t stream)
{
    const float* x       = (const float*)d_in[0];
    const float* raw_win = (const float*)d_in[1];
    const float* raw_hop = (const float*)d_in[2];
    float* out = (float*)d_out;

    int* perm = nullptr;
    if (d_ws != nullptr && ws_size >= 4096) {
        perm = (int*)d_ws;
        dstft_perm<<<1, 512, 0, stream>>>(raw_win, perm);
    }
    const int stft_mode = (out_size >= 3 * BFT) ? 2 : 1;
    dstft_main<<<dim3(9, FRAMES), 64 * NWAVE, 0, stream>>>(
        x, raw_win, raw_hop, perm, out, out_size, stft_mode);
}

// Round 7
// 69.372 us; speedup vs baseline: 1.8994x; 1.2558x over previous
//
#include <hip/hip_runtime.h>
#include <math.h>

#define NFFT   1024
#define FREQ   513
#define FRAMES 256
#define SIGLEN 66560          // 256*256 + 1024
#define NB     4
#define BFT    (NB * FREQ * FRAMES)   // 525312
#define NWAVE  8               // waves per block (n-loop split factor)
#define NCHUNK 9               // ceil(513/64)
#define UNITS  (NCHUNK * FRAMES)      // 2304
#define GRID   (UNITS / 2)            // 1152 snake-paired blocks

// ---------------------------------------------------------------------------
// perm = argsort(theta) DESCENDING, stable (O(F^2) rank). Needs 2052 B of ws.
// ---------------------------------------------------------------------------
__global__ __launch_bounds__(1024)
void dstft_perm(const float* __restrict__ raw_win, int* __restrict__ perm)
{
    __shared__ float th[FREQ];
    const int tid = threadIdx.x;
    if (tid < FREQ)
        th[tid] = 10.0f + 1014.0f / (1.0f + expf(-raw_win[tid]));
    __syncthreads();
    if (tid < FREQ) {
        const float ti = th[tid];
        int r = 0;
        for (int j = 0; j < FREQ; ++j) {
            const float tj = th[j];
            r += (tj > ti) || (tj == ti && j < tid);   // descending, stable
        }
        perm[r] = tid;
    }
}

__device__ __forceinline__ float sigmoid_f32(float v)
{
    if (v >= 0.0f) {
        return 1.0f / (1.0f + expf(-v));
    } else {
        const float e = expf(v);
        return e / (1.0f + e);
    }
}

__device__ __forceinline__ float rfl_f32(float v)
{
    return __int_as_float(__builtin_amdgcn_readfirstlane(__float_as_int(v)));
}

// ---------------------------------------------------------------------------
// Block = 8 waves = 512 thr. Snake schedule: block b -> units {b, 2303-b}
// (units are chunk-major over descending-theta chunks -> per-block work is
// near-constant). Per unit: stage x[base..base+1024) x 4 batches into LDS as
// float4 rows; 8 waves split the window support; inner loop reads 4 batch
// samples with ONE uniform ds_read_b128 (broadcast). Combine via LDS.
// ---------------------------------------------------------------------------
__global__ __launch_bounds__(64 * NWAVE)
void dstft_main(const float* __restrict__ x,
                const float* __restrict__ raw_win,
                const float* __restrict__ raw_hop,
                const int* __restrict__ perm,      // may be null (unsorted)
                float* __restrict__ out, int out_size, int stft_mode)
{
    const int tid  = threadIdx.x;
    const int lane = tid & 63;
    const int q    = tid >> 6;               // wave id = n-segment id

    __shared__ float4 xlds[NFFT];            // 16 KB: [n] = {b0,b1,b2,b3}
    __shared__ float  part[NWAVE][64][9];    // 18 KB

    const float hop = 1.0f + sigmoid_f32(raw_hop[0]) * 255.0f;

#pragma unroll 1
    for (int uu = 0; uu < 2; ++uu) {
        const int u     = uu ? (UNITS - 1 - (int)blockIdx.x) : (int)blockIdx.x;
        const int chunk = u >> 8;            // 0..8 (desc-theta order)
        const int t     = u & 255;
        const int spos  = chunk * 64 + lane;
        const bool active = (spos < FREQ);

        int f = 0;
        if (active) {
            f = perm ? perm[spos] : spos;
            f = (f < 0) ? 0 : ((f > FREQ - 1) ? (FREQ - 1) : f);
        }
        const float theta = active
            ? (10.0f + sigmoid_f32(raw_win[f]) * 1014.0f)
            : 10.0f;

        // wave-wide max theta -> SGPR
        float tmaxv = theta;
#pragma unroll
        for (int s = 32; s; s >>= 1)
            tmaxv = fmaxf(tmaxv, __shfl_xor(tmaxv, s, 64));
        const float tmax = rfl_f32(tmaxv);

        // pos/floor: f32-canonical replication of the reference (uniform)
        float pos = (float)t * hop;
        pos = fminf(fmaxf(pos, 0.0f), 65536.0f);
        const float fl   = floorf(pos);
        const int   base = __builtin_amdgcn_readfirstlane((int)fl);
        const float c    = rfl_f32(511.5f + (pos - fl));

        // ---- stage x tile into LDS (protect reuse across units) ----
        if (uu) __syncthreads();
#pragma unroll
        for (int n = tid; n < NFFT; n += 64 * NWAVE) {
            float4 v;
            v.x = x[base + n];
            v.y = x[base + n + SIGLEN];
            v.z = x[base + n + 2 * SIGLEN];
            v.w = x[base + n + 3 * SIGLEN];
            xlds[n] = v;
        }
        __syncthreads();

        int lo = (int)floorf(c - 0.5f * tmax);
        int hi = (int)ceilf (c + 0.5f * tmax);
        lo = lo > 0 ? lo : 0;
        hi = hi < (NFFT - 1) ? hi : (NFFT - 1);
        int cnt = hi - lo + 1;
        cnt = cnt < 0 ? 0 : (cnt > NFFT ? NFFT : cnt);
        lo  = __builtin_amdgcn_readfirstlane(lo);
        cnt = __builtin_amdgcn_readfirstlane(cnt);

        const int s0     = lo + (cnt * q) / NWAVE;
        const int s1     = lo + (cnt * (q + 1)) / NWAVE;
        const int segcnt = s1 - s0;

        const float invth = 1.0f / theta;
        float r = ((float)s0 - c) * invth;   // window arg, revolutions

        // phasor init at n=s0 and step: exact int reduction + hw trig (rev)
        const float sdr = (float)f * (1.0f / 1024.0f);
        const float cd  = __builtin_amdgcn_cosf(sdr);
        const float sd  = __builtin_amdgcn_sinf(sdr);
        int m0 = (f * s0) & (NFFT - 1);
        m0 = (m0 >= 512) ? (m0 - 1024) : m0;
        const float p0 = (float)m0 * (1.0f / 1024.0f);
        float ca = __builtin_amdgcn_cosf(p0);
        float sa = __builtin_amdgcn_sinf(p0);

        float re0 = 0.f, re1 = 0.f, re2 = 0.f, re3 = 0.f;
        float sm0 = 0.f, sm1 = 0.f, sm2 = 0.f, sm3 = 0.f;

        const float4* __restrict__ xp = &xlds[s0];
#pragma unroll 4
        for (int i = 0; i < segcnt; ++i) {
            const float cw = __builtin_amdgcn_cosf(r);     // cos(2*pi*r)
            const float w  = (fabsf(r) <= 0.5f) ? fmaf(0.5f, cw, 0.5f) : 0.0f;
            const float wc  = w * ca;
            const float wsn = w * sa;
            const float4 v = xp[i];                        // ds_read_b128
            re0 = fmaf(v.x, wc, re0);  sm0 = fmaf(v.x, wsn, sm0);
            re1 = fmaf(v.y, wc, re1);  sm1 = fmaf(v.y, wsn, sm1);
            re2 = fmaf(v.z, wc, re2);  sm2 = fmaf(v.z, wsn, sm2);
            re3 = fmaf(v.w, wc, re3);  sm3 = fmaf(v.w, wsn, sm3);
            const float nca = fmaf(ca, cd, -(sa * sd));
            const float nsa = fmaf(sa, cd,   ca * sd);
            ca = nca; sa = nsa;
            r += invth;
        }

        // ---- cross-wave combine via LDS ----
        part[q][lane][0] = re0;  part[q][lane][1] = re1;
        part[q][lane][2] = re2;  part[q][lane][3] = re3;
        part[q][lane][4] = sm0;  part[q][lane][5] = sm1;
        part[q][lane][6] = sm2;  part[q][lane][7] = sm3;
        __syncthreads();

        if (tid < 64 && active) {
            float res[NB] = {0.f, 0.f, 0.f, 0.f};
            float sms[NB] = {0.f, 0.f, 0.f, 0.f};
#pragma unroll
            for (int p = 0; p < NWAVE; ++p) {
#pragma unroll
                for (int b = 0; b < NB; ++b) {
                    res[b] += part[p][tid][b];
                    sms[b] += part[p][tid][4 + b];
                }
            }
            const int ftBase = f * FRAMES + t;
#pragma unroll
            for (int b = 0; b < NB; ++b) {
                const int   idx = b * (FREQ * FRAMES) + ftBase;
                const float re  = res[b];
                const float im  = -sms[b];
                if (idx < out_size)
                    out[idx] = sqrtf(fmaf(re, re, im * im)) + 1e-12f;
                if (stft_mode == 2) {
                    if (BFT + 2 * idx + 1 < out_size) {
                        out[BFT + 2 * idx]     = re;
                        out[BFT + 2 * idx + 1] = im;
                    }
                } else {
                    if (BFT + idx < out_size)
                        out[BFT + idx] = re;   // complex stored as f32 real
                }
            }
        }
    }
}

// ---------------------------------------------------------------------------
extern "C" void kernel_launch(void* const* d_in, const int* in_sizes, int n_in,
                              void* d_out, int out_size, void* d_ws, size_t ws_size,
                              hipStream_t stream)
{
    const float* x       = (const float*)d_in[0];
    const float* raw_win = (const float*)d_in[1];
    const float* raw_hop = (const float*)d_in[2];
    float* out = (float*)d_out;

    int* perm = nullptr;
    if (d_ws != nullptr && ws_size >= 4096) {
        perm = (int*)d_ws;
        dstft_perm<<<1, 1024, 0, stream>>>(raw_win, perm);
    }
    const int stft_mode = (out_size >= 3 * BFT) ? 2 : 1;
    dstft_main<<<GRID, 64 * NWAVE, 0, stream>>>(
        x, raw_win, raw_hop, perm, out, out_size, stft_mode);
}

// Round 8
// 64.434 us; speedup vs baseline: 2.0450x; 1.0766x over previous
//
#include <hip/hip_runtime.h>
#include <math.h>

#define NFFT   1024
#define FREQ   513
#define FRAMES 256
#define SIGLEN 66560          // 256*256 + 1024
#define NB     4
#define BFT    (NB * FREQ * FRAMES)   // 525312
#define NWAVE  4               // waves per block (n-loop split factor)
#define NCHUNK 9               // ceil(513/64)
#define UNITS  (NCHUNK * FRAMES)      // 2304
#define GRID   (UNITS / 2)            // 1152 snake-paired blocks

// ---------------------------------------------------------------------------
// perm = argsort(theta) DESCENDING, stable (O(F^2) rank). Needs 2052 B of ws.
// ---------------------------------------------------------------------------
__global__ __launch_bounds__(1024)
void dstft_perm(const float* __restrict__ raw_win, int* __restrict__ perm)
{
    __shared__ float th[FREQ];
    const int tid = threadIdx.x;
    if (tid < FREQ)
        th[tid] = 10.0f + 1014.0f / (1.0f + expf(-raw_win[tid]));
    __syncthreads();
    if (tid < FREQ) {
        const float ti = th[tid];
        int r = 0;
        for (int j = 0; j < FREQ; ++j) {
            const float tj = th[j];
            r += (tj > ti) || (tj == ti && j < tid);   // descending, stable
        }
        perm[r] = tid;
    }
}

__device__ __forceinline__ float sigmoid_f32(float v)
{
    if (v >= 0.0f) {
        return 1.0f / (1.0f + expf(-v));
    } else {
        const float e = expf(v);
        return e / (1.0f + e);
    }
}

__device__ __forceinline__ float rfl_f32(float v)
{
    return __int_as_float(__builtin_amdgcn_readfirstlane(__float_as_int(v)));
}

// ---------------------------------------------------------------------------
// Block = 4 waves = 256 thr. Snake: block b -> units {b, 2303-b} (pair sums
// of sorted-theta chunk maxima are ~constant by sigmoid symmetry). Per unit:
// stage x[base..base+1024) x 4 batches into LDS float4 rows; 4 waves split
// the window support; inner loop: 1 uniform ds_read_b128 + ~18 VALU.
// 256-thr blocks => all 4.5 blocks/CU co-resident (no serial rounds).
// ---------------------------------------------------------------------------
__global__ __launch_bounds__(64 * NWAVE)
void dstft_main(const float* __restrict__ x,
                const float* __restrict__ raw_win,
                const float* __restrict__ raw_hop,
                const int* __restrict__ perm,      // may be null (unsorted)
                float* __restrict__ out, int out_size, int stft_mode)
{
    const int tid  = threadIdx.x;
    const int lane = tid & 63;
    const int q    = tid >> 6;               // wave id = n-segment id

    __shared__ float4 xlds[NFFT];            // 16 KB: [n] = {b0,b1,b2,b3}
    __shared__ float  part[NWAVE][64][9];    // 9 KB

    const float hop = 1.0f + sigmoid_f32(raw_hop[0]) * 255.0f;

#pragma unroll 1
    for (int uu = 0; uu < 2; ++uu) {
        const int u     = uu ? (UNITS - 1 - (int)blockIdx.x) : (int)blockIdx.x;
        const int chunk = u >> 8;            // 0..8 (desc-theta order)
        const int t     = u & 255;
        const int spos  = chunk * 64 + lane;
        const bool active = (spos < FREQ);

        int f = 0;
        if (active) {
            f = perm ? perm[spos] : spos;
            f = (f < 0) ? 0 : ((f > FREQ - 1) ? (FREQ - 1) : f);
        }
        const float theta = active
            ? (10.0f + sigmoid_f32(raw_win[f]) * 1014.0f)
            : 10.0f;

        // wave-wide max theta -> SGPR
        float tmaxv = theta;
#pragma unroll
        for (int s = 32; s; s >>= 1)
            tmaxv = fmaxf(tmaxv, __shfl_xor(tmaxv, s, 64));
        const float tmax = rfl_f32(tmaxv);

        // pos/floor: f32-canonical replication of the reference (uniform)
        float pos = (float)t * hop;
        pos = fminf(fmaxf(pos, 0.0f), 65536.0f);
        const float fl   = floorf(pos);
        const int   base = __builtin_amdgcn_readfirstlane((int)fl);
        const float c    = rfl_f32(511.5f + (pos - fl));

        // ---- stage x tile into LDS ----
        if (uu) __syncthreads();
#pragma unroll
        for (int n = tid; n < NFFT; n += 64 * NWAVE) {
            float4 v;
            v.x = x[base + n];
            v.y = x[base + n + SIGLEN];
            v.z = x[base + n + 2 * SIGLEN];
            v.w = x[base + n + 3 * SIGLEN];
            xlds[n] = v;
        }
        __syncthreads();

        int lo = (int)floorf(c - 0.5f * tmax);
        int hi = (int)ceilf (c + 0.5f * tmax);
        lo = lo > 0 ? lo : 0;
        hi = hi < (NFFT - 1) ? hi : (NFFT - 1);
        int cnt = hi - lo + 1;
        cnt = cnt < 0 ? 0 : (cnt > NFFT ? NFFT : cnt);
        lo  = __builtin_amdgcn_readfirstlane(lo);
        cnt = __builtin_amdgcn_readfirstlane(cnt);

        const int s0     = lo + (cnt * q) / NWAVE;
        const int s1     = lo + (cnt * (q + 1)) / NWAVE;
        const int segcnt = s1 - s0;

        const float invth = 1.0f / theta;
        float r = ((float)s0 - c) * invth;   // window arg, revolutions

        // phasor init at n=s0 and step: exact int reduction + hw trig (rev)
        const float sdr = (float)f * (1.0f / 1024.0f);
        const float cd  = __builtin_amdgcn_cosf(sdr);
        const float sd  = __builtin_amdgcn_sinf(sdr);
        int m0 = (f * s0) & (NFFT - 1);
        m0 = (m0 >= 512) ? (m0 - 1024) : m0;
        const float p0 = (float)m0 * (1.0f / 1024.0f);
        float ca = __builtin_amdgcn_cosf(p0);
        float sa = __builtin_amdgcn_sinf(p0);

        float re0 = 0.f, re1 = 0.f, re2 = 0.f, re3 = 0.f;
        float sm0 = 0.f, sm1 = 0.f, sm2 = 0.f, sm3 = 0.f;

        const float4* __restrict__ xp = &xlds[s0];
#pragma unroll 4
        for (int i = 0; i < segcnt; ++i) {
            // clamp -> v_med3; cos(2*pi*(+-0.5)) = -1 -> w = 0 outside support
            const float rc = fminf(fmaxf(r, -0.5f), 0.5f);
            const float w  = fmaf(0.5f, __builtin_amdgcn_cosf(rc), 0.5f);
            const float wc  = w * ca;
            const float wsn = w * sa;
            const float4 v = xp[i];                        // ds_read_b128
            re0 = fmaf(v.x, wc, re0);  sm0 = fmaf(v.x, wsn, sm0);
            re1 = fmaf(v.y, wc, re1);  sm1 = fmaf(v.y, wsn, sm1);
            re2 = fmaf(v.z, wc, re2);  sm2 = fmaf(v.z, wsn, sm2);
            re3 = fmaf(v.w, wc, re3);  sm3 = fmaf(v.w, wsn, sm3);
            const float nca = fmaf(ca, cd, -(sa * sd));
            const float nsa = fmaf(sa, cd,   ca * sd);
            ca = nca; sa = nsa;
            r += invth;
        }

        // ---- cross-wave combine via LDS ----
        part[q][lane][0] = re0;  part[q][lane][1] = re1;
        part[q][lane][2] = re2;  part[q][lane][3] = re3;
        part[q][lane][4] = sm0;  part[q][lane][5] = sm1;
        part[q][lane][6] = sm2;  part[q][lane][7] = sm3;
        __syncthreads();

        if (tid < 64 && active) {
            float res[NB] = {0.f, 0.f, 0.f, 0.f};
            float sms[NB] = {0.f, 0.f, 0.f, 0.f};
#pragma unroll
            for (int p = 0; p < NWAVE; ++p) {
#pragma unroll
                for (int b = 0; b < NB; ++b) {
                    res[b] += part[p][tid][b];
                    sms[b] += part[p][tid][4 + b];
                }
            }
            const int ftBase = f * FRAMES + t;
#pragma unroll
            for (int b = 0; b < NB; ++b) {
                const int   idx = b * (FREQ * FRAMES) + ftBase;
                const float re  = res[b];
                const float im  = -sms[b];
                if (idx < out_size)
                    out[idx] = sqrtf(fmaf(re, re, im * im)) + 1e-12f;
                if (stft_mode == 2) {
                    if (BFT + 2 * idx + 1 < out_size) {
                        out[BFT + 2 * idx]     = re;
                        out[BFT + 2 * idx + 1] = im;
                    }
                } else {
                    if (BFT + idx < out_size)
                        out[BFT + idx] = re;   // complex stored as f32 real
                }
            }
        }
    }
}

// ---------------------------------------------------------------------------
extern "C" void kernel_launch(void* const* d_in, const int* in_sizes, int n_in,
                              void* d_out, int out_size, void* d_ws, size_t ws_size,
                              hipStream_t stream)
{
    const float* x       = (const float*)d_in[0];
    const float* raw_win = (const float*)d_in[1];
    const float* raw_hop = (const float*)d_in[2];
    float* out = (float*)d_out;

    int* perm = nullptr;
    if (d_ws != nullptr && ws_size >= 4096) {
        perm = (int*)d_ws;
        dstft_perm<<<1, 1024, 0, stream>>>(raw_win, perm);
    }
    const int stft_mode = (out_size >= 3 * BFT) ? 2 : 1;
    dstft_main<<<GRID, 64 * NWAVE, 0, stream>>>(
        x, raw_win, raw_hop, perm, out, out_size, stft_mode);
}

// Round 9
// 57.485 us; speedup vs baseline: 2.2922x; 1.1209x over previous
//
#include <hip/hip_runtime.h>
#include <math.h>

#define NFFT   1024
#define FREQ   513
#define FRAMES 256
#define SIGLEN 66560          // 256*256 + 1024
#define NB     4
#define BFT    (NB * FREQ * FRAMES)   // 525312
#define NWAVE  4               // waves per block (n-loop split factor)
#define NCHUNK 9               // ceil(513/64)
#define UNITS  (NCHUNK * FRAMES)      // 2304 blocks, 1 unit each (LPT order)

// ---------------------------------------------------------------------------
// perm = argsort(theta) DESCENDING, stable (O(F^2) rank). Needs 2052 B of ws.
// ---------------------------------------------------------------------------
__global__ __launch_bounds__(1024)
void dstft_perm(const float* __restrict__ raw_win, int* __restrict__ perm)
{
    __shared__ float th[FREQ];
    const int tid = threadIdx.x;
    if (tid < FREQ)
        th[tid] = 10.0f + 1014.0f / (1.0f + expf(-raw_win[tid]));
    __syncthreads();
    if (tid < FREQ) {
        const float ti = th[tid];
        int r = 0;
        for (int j = 0; j < FREQ; ++j) {
            const float tj = th[j];
            r += (tj > ti) || (tj == ti && j < tid);   // descending, stable
        }
        perm[r] = tid;
    }
}

__device__ __forceinline__ float sigmoid_f32(float v)
{
    if (v >= 0.0f) {
        return 1.0f / (1.0f + expf(-v));
    } else {
        const float e = expf(v);
        return e / (1.0f + e);
    }
}

__device__ __forceinline__ float rfl_f32(float v)
{
    return __int_as_float(__builtin_amdgcn_readfirstlane(__float_as_int(v)));
}

// ---------------------------------------------------------------------------
// Block = 4 waves = 256 thr, ONE unit (t, 64-f chunk) per block. 2304 blocks
// in descending-theta order => LPT scheduling. x staged into LDS float4 rows
// over [lo,hi] only; part[] aliases xlds (disjoint in time, sync-separated)
// => 16.4 KB LDS => 8 blocks/CU (wave-capped, 32 waves/CU nominal).
// ---------------------------------------------------------------------------
__global__ __launch_bounds__(64 * NWAVE)
void dstft_main(const float* __restrict__ x,
                const float* __restrict__ raw_win,
                const float* __restrict__ raw_hop,
                const int* __restrict__ perm,      // may be null (unsorted)
                float* __restrict__ out, int out_size, int stft_mode)
{
    const int tid  = threadIdx.x;
    const int lane = tid & 63;
    const int q    = tid >> 6;               // wave id = n-segment id

    // xlds (16 KB) and part (9 KB) alias: part is only touched after the
    // __syncthreads that ends all xlds reads.
    __shared__ __align__(16) unsigned char smem[NFFT * sizeof(float4)];
    float4* xlds = reinterpret_cast<float4*>(smem);
    float (*part)[64][9] = reinterpret_cast<float (*)[64][9]>(smem);

    const int u     = (int)blockIdx.x;
    const int chunk = u >> 8;                // 0..8 (desc-theta order)
    const int t     = u & 255;
    const int spos  = chunk * 64 + lane;
    const bool active = (spos < FREQ);

    int f = 0;
    if (active) {
        f = perm ? perm[spos] : spos;
        f = (f < 0) ? 0 : ((f > FREQ - 1) ? (FREQ - 1) : f);
    }
    const float theta = active
        ? (10.0f + sigmoid_f32(raw_win[f]) * 1014.0f)
        : 10.0f;

    // wave-wide max theta -> SGPR
    float tmaxv = theta;
#pragma unroll
    for (int s = 32; s; s >>= 1)
        tmaxv = fmaxf(tmaxv, __shfl_xor(tmaxv, s, 64));
    const float tmax = rfl_f32(tmaxv);

    // pos/floor: f32-canonical replication of the reference (uniform)
    const float hop = 1.0f + sigmoid_f32(raw_hop[0]) * 255.0f;
    float pos = (float)t * hop;
    pos = fminf(fmaxf(pos, 0.0f), 65536.0f);
    const float fl   = floorf(pos);
    const int   base = __builtin_amdgcn_readfirstlane((int)fl);
    const float c    = rfl_f32(511.5f + (pos - fl));

    int lo = (int)floorf(c - 0.5f * tmax);
    int hi = (int)ceilf (c + 0.5f * tmax);
    lo = lo > 0 ? lo : 0;
    hi = hi < (NFFT - 1) ? hi : (NFFT - 1);
    int cnt = hi - lo + 1;
    cnt = cnt < 0 ? 0 : (cnt > NFFT ? NFFT : cnt);
    lo  = __builtin_amdgcn_readfirstlane(lo);
    cnt = __builtin_amdgcn_readfirstlane(cnt);

    // ---- stage x tile [lo, lo+cnt) into LDS (coalesced) ----
    for (int n = lo + tid; n < lo + cnt; n += 64 * NWAVE) {
        float4 v;
        v.x = x[base + n];
        v.y = x[base + n + SIGLEN];
        v.z = x[base + n + 2 * SIGLEN];
        v.w = x[base + n + 3 * SIGLEN];
        xlds[n] = v;
    }
    __syncthreads();

    const int s0     = lo + (cnt * q) / NWAVE;
    const int s1     = lo + (cnt * (q + 1)) / NWAVE;
    const int segcnt = s1 - s0;

    const float invth = 1.0f / theta;
    float r = ((float)s0 - c) * invth;       // window arg, revolutions

    // phasor init at n=s0 and step: exact int reduction + hw trig (rev)
    const float sdr = (float)f * (1.0f / 1024.0f);
    const float cd  = __builtin_amdgcn_cosf(sdr);
    const float sd  = __builtin_amdgcn_sinf(sdr);
    int m0 = (f * s0) & (NFFT - 1);
    m0 = (m0 >= 512) ? (m0 - 1024) : m0;
    const float p0 = (float)m0 * (1.0f / 1024.0f);
    float ca = __builtin_amdgcn_cosf(p0);
    float sa = __builtin_amdgcn_sinf(p0);

    float re0 = 0.f, re1 = 0.f, re2 = 0.f, re3 = 0.f;
    float sm0 = 0.f, sm1 = 0.f, sm2 = 0.f, sm3 = 0.f;

    const float4* __restrict__ xp = &xlds[s0];
#pragma unroll 4
    for (int i = 0; i < segcnt; ++i) {
        // clamp -> v_med3; cos(2*pi*(+-0.5)) = -1 -> w = 0 outside support
        const float rc = fminf(fmaxf(r, -0.5f), 0.5f);
        const float w  = fmaf(0.5f, __builtin_amdgcn_cosf(rc), 0.5f);
        const float wc  = w * ca;
        const float wsn = w * sa;
        const float4 v = xp[i];                        // ds_read_b128
        re0 = fmaf(v.x, wc, re0);  sm0 = fmaf(v.x, wsn, sm0);
        re1 = fmaf(v.y, wc, re1);  sm1 = fmaf(v.y, wsn, sm1);
        re2 = fmaf(v.z, wc, re2);  sm2 = fmaf(v.z, wsn, sm2);
        re3 = fmaf(v.w, wc, re3);  sm3 = fmaf(v.w, wsn, sm3);
        const float nca = fmaf(ca, cd, -(sa * sd));
        const float nsa = fmaf(sa, cd,   ca * sd);
        ca = nca; sa = nsa;
        r += invth;
    }

    // ---- cross-wave combine; part aliases xlds, so fence reads first ----
    __syncthreads();
    part[q][lane][0] = re0;  part[q][lane][1] = re1;
    part[q][lane][2] = re2;  part[q][lane][3] = re3;
    part[q][lane][4] = sm0;  part[q][lane][5] = sm1;
    part[q][lane][6] = sm2;  part[q][lane][7] = sm3;
    __syncthreads();

    if (tid < 64 && active) {
        float res[NB] = {0.f, 0.f, 0.f, 0.f};
        float sms[NB] = {0.f, 0.f, 0.f, 0.f};
#pragma unroll
        for (int p = 0; p < NWAVE; ++p) {
#pragma unroll
            for (int b = 0; b < NB; ++b) {
                res[b] += part[p][tid][b];
                sms[b] += part[p][tid][4 + b];
            }
        }
        const int ftBase = f * FRAMES + t;
#pragma unroll
        for (int b = 0; b < NB; ++b) {
            const int   idx = b * (FREQ * FRAMES) + ftBase;
            const float re  = res[b];
            const float im  = -sms[b];
            if (idx < out_size)
                out[idx] = sqrtf(fmaf(re, re, im * im)) + 1e-12f;
            if (stft_mode == 2) {
                if (BFT + 2 * idx + 1 < out_size) {
                    out[BFT + 2 * idx]     = re;
                    out[BFT + 2 * idx + 1] = im;
                }
            } else {
                if (BFT + idx < out_size)
                    out[BFT + idx] = re;     // complex stored as f32 real
            }
        }
    }
}

// ---------------------------------------------------------------------------
extern "C" void kernel_launch(void* const* d_in, const int* in_sizes, int n_in,
                              void* d_out, int out_size, void* d_ws, size_t ws_size,
                              hipStream_t stream)
{
    const float* x       = (const float*)d_in[0];
    const float* raw_win = (const float*)d_in[1];
    const float* raw_hop = (const float*)d_in[2];
    float* out = (float*)d_out;

    int* perm = nullptr;
    if (d_ws != nullptr && ws_size >= 4096) {
        perm = (int*)d_ws;
        dstft_perm<<<1, 1024, 0, stream>>>(raw_win, perm);
    }
    const int stft_mode = (out_size >= 3 * BFT) ? 2 : 1;
    dstft_main<<<UNITS, 64 * NWAVE, 0, stream>>>(
        x, raw_win, raw_hop, perm, out, out_size, stft_mode);
}